// Round 4
// baseline (228.816 us; speedup 1.0000x reference)
//
#include <hip/hip_runtime.h>
#include <hip/hip_bf16.h>

#define BB 2048   // sentences
#define LL 64     // maxlen
#define SS 2048   // seeds
#define LSEED 8   // maxlen_seed
#define CC 64     // clusters
#define DD 300    // embedding dim
#define NC4 75    // DD / 4 float4 chunks
#define KP 320    // padded K for bf16 MFMA (10 x 32)

typedef __attribute__((ext_vector_type(8))) short short8;
typedef __attribute__((ext_vector_type(4))) float f32x4;

// ---- order-preserving float <-> uint for atomicMax ----
__device__ __forceinline__ unsigned enc_f(float f) {
    unsigned u = __float_as_uint(f);
    return (u & 0x80000000u) ? ~u : (u | 0x80000000u);
}
__device__ __forceinline__ float dec_f(unsigned k) {
    unsigned u = (k & 0x80000000u) ? (k ^ 0x80000000u) : ~k;
    return __uint_as_float(u);
}
// float -> bf16 bits, RNE
__device__ __forceinline__ unsigned short f2bf(float f) {
    unsigned u = __float_as_uint(f);
    u += 0x7fffu + ((u >> 16) & 1u);
    return (unsigned short)(u >> 16);
}
__device__ __forceinline__ void gload_lds16(const void* g, void* l) {
    __builtin_amdgcn_global_load_lds(
        (const __attribute__((address_space(1))) void*)g,
        (__attribute__((address_space(3))) void*)l, 16, 0, 0);
}

// ---- pooling (float4 gather) + fused init of keys/seg/out/cnt ----
// At the pattern wall (~3.2 TB/s L2-miss traffic on random 1200B rows) — do not churn.
__global__ __launch_bounds__(256) void pool_kernel(
    const int* __restrict__ sents, const int* __restrict__ seeds,
    const int* __restrict__ lens, const float* __restrict__ mask,
    const float* __restrict__ emb_t, const float* __restrict__ emb_s,
    unsigned short* __restrict__ snt_t, unsigned short* __restrict__ snt_s,
    unsigned short* __restrict__ sd_t, unsigned short* __restrict__ sd_s,
    unsigned* __restrict__ keys_all, int* __restrict__ seg,
    unsigned* __restrict__ cnt, float* __restrict__ out0) {
    const int bid = blockIdx.x, tid = threadIdx.x;

    // fused init: zero atomic-max keys (64 per block covers 2*BB*CC exactly)
    if (tid < 64) keys_all[bid * 64 + tid] = 0u;
    if (bid == 0) {
        if (tid == 0) *out0 = 0.f;
        if (tid < 16) cnt[tid] = 0u;
        // segment ids for all SS seeds: 8 per thread
        for (int i = tid * 8; i < tid * 8 + 8; i++) {
            int c = 0, cum = lens[0];
            while (i >= cum && c < CC - 1) { c++; cum += lens[c]; }
            seg[i] = c;
        }
    }

    __shared__ float4 pt[3 * NC4];
    __shared__ float4 ps[3 * NC4];
    __shared__ int toks[LL];
    __shared__ float msk[LL];
    __shared__ float denom_sh;

    const int g = tid / NC4;          // 0..2 (tid>=225 idle in gather)
    const int c = tid - g * NC4;      // float4 chunk within row

    if (bid < BB) {
        const int b = bid;
        if (tid < LL) {   // wave 0 exactly
            float v = mask[b * LL + tid];
            msk[tid] = v;
            toks[tid] = sents[b * LL + tid];
#pragma unroll
            for (int d = 32; d; d >>= 1) v += __shfl_xor(v, d);
            if (tid == 0) denom_sh = fmaxf(v, 1.0f);
        }
        __syncthreads();
        if (g < 3) {
            float4 at = {0.f, 0.f, 0.f, 0.f}, as = {0.f, 0.f, 0.f, 0.f};
#pragma unroll 4
            for (int l = g; l < LL; l += 3) {
                size_t o = (size_t)toks[l] * DD;
                float m = msk[l];
                float4 vt = *(const float4*)(emb_t + o + 4 * c);
                float4 vs = *(const float4*)(emb_s + o + 4 * c);
                at.x = fmaf(m, vt.x, at.x); at.y = fmaf(m, vt.y, at.y);
                at.z = fmaf(m, vt.z, at.z); at.w = fmaf(m, vt.w, at.w);
                as.x = fmaf(m, vs.x, as.x); as.y = fmaf(m, vs.y, as.y);
                as.z = fmaf(m, vs.z, as.z); as.w = fmaf(m, vs.w, as.w);
            }
            pt[g * NC4 + c] = at;
            ps[g * NC4 + c] = as;
        }
        __syncthreads();
        float scale = 1.0f / denom_sh;
        if (tid < 150) {
            int table = tid / NC4, cc = tid - table * NC4;
            const float4* P = table ? ps : pt;
            float4 a = P[cc], b2 = P[NC4 + cc], d2 = P[2 * NC4 + cc];
            ushort4 o;
            o.x = f2bf((a.x + b2.x + d2.x) * scale);
            o.y = f2bf((a.y + b2.y + d2.y) * scale);
            o.z = f2bf((a.z + b2.z + d2.z) * scale);
            o.w = f2bf((a.w + b2.w + d2.w) * scale);
            unsigned short* dst = (table ? snt_s : snt_t) + (size_t)b * KP + 4 * cc;
            *(ushort4*)dst = o;
        } else if (tid >= 160 && tid < 170) {  // zero tail dims [300,320)
            int k = tid - 160;                  // 0..9 -> 2 tables x 5 chunks
            unsigned short* dst = ((k < 5) ? snt_t : snt_s) + (size_t)b * KP + 300 + 4 * (k % 5);
            *(ushort4*)dst = (ushort4){0, 0, 0, 0};
        }
    } else {
        const int s = bid - BB;
        if (tid < LSEED) toks[tid] = seeds[s * LSEED + tid];
        __syncthreads();
        if (g < 3) {
            float4 at = {0.f, 0.f, 0.f, 0.f}, as = {0.f, 0.f, 0.f, 0.f};
#pragma unroll
            for (int l = g; l < LSEED; l += 3) {
                size_t o = (size_t)toks[l] * DD;
                float4 vt = *(const float4*)(emb_t + o + 4 * c);
                float4 vs = *(const float4*)(emb_s + o + 4 * c);
                at.x += vt.x; at.y += vt.y; at.z += vt.z; at.w += vt.w;
                as.x += vs.x; as.y += vs.y; as.z += vs.z; as.w += vs.w;
            }
            pt[g * NC4 + c] = at;
            ps[g * NC4 + c] = as;
        }
        __syncthreads();
        const float scale = 1.0f / LSEED;
        if (tid < 150) {
            int table = tid / NC4, cc = tid - table * NC4;
            const float4* P = table ? ps : pt;
            float4 a = P[cc], b2 = P[NC4 + cc], d2 = P[2 * NC4 + cc];
            ushort4 o;
            o.x = f2bf((a.x + b2.x + d2.x) * scale);
            o.y = f2bf((a.y + b2.y + d2.y) * scale);
            o.z = f2bf((a.z + b2.z + d2.z) * scale);
            o.w = f2bf((a.w + b2.w + d2.w) * scale);
            unsigned short* dst = (table ? sd_s : sd_t) + (size_t)s * KP + 4 * cc;
            *(ushort4*)dst = o;
        } else if (tid >= 160 && tid < 170) {
            int k = tid - 160;
            unsigned short* dst = ((k < 5) ? sd_t : sd_s) + (size_t)s * KP + 300 + 4 * (k % 5);
            *(ushort4*)dst = (ushort4){0, 0, 0, 0};
        }
    }
}

// ---- bf16 MFMA GEMM, double-buffered async staging, fused segment-max + last-block loss ----
__global__ __launch_bounds__(256) void gemm_max_kernel(
    const unsigned short* __restrict__ snt_t, const unsigned short* __restrict__ snt_s,
    const unsigned short* __restrict__ sd_t, const unsigned short* __restrict__ sd_s,
    const int* __restrict__ seg,
    unsigned* __restrict__ keys_t, unsigned* __restrict__ keys_s,
    unsigned* __restrict__ cnt, float* __restrict__ out) {
    const int branch = blockIdx.z;
    const unsigned short* Ag = branch ? snt_s : snt_t;
    const unsigned short* Bg = branch ? sd_s : sd_t;
    unsigned* keys = branch ? keys_s : keys_t;

    const int tid = threadIdx.x;
    const int wave = tid >> 6, lane = tid & 63;
    const int quad = lane >> 4, l16 = lane & 15;
    const int wm = wave >> 1, wn = wave & 1;   // 2x2 wave grid, 64x64 per wave
    const int row0 = blockIdx.y * 128, col0 = blockIdx.x * 128;

    // smem: dbuf staging (2 x (A+B) x 128 x 32 bf16 = 32768 B) unioned with
    //       D half-tile (128 x 66 f32 = 33792 B); segs at 33792
    __shared__ __align__(16) char smem[33792 + 512];
    unsigned short* Sb = (unsigned short*)smem;  // [buf][A/B][128][32]
    float* Dl = (float*)smem;                     // [128][66]
    int* segs = (int*)(smem + 33792);
    __shared__ unsigned last_sh;

    if (tid < 128) segs[tid] = seg[col0 + tid];

    const int lr = lane >> 2, lp = lane & 3;   // staging: 4 lanes per row

    f32x4 acc[4][4];
#pragma unroll
    for (int i = 0; i < 4; i++)
#pragma unroll
        for (int j = 0; j < 4; j++) acc[i][j] = (f32x4)0.f;

    // stage K-chunk kt into buffer kt&1
    auto stage = [&](int kt) {
        const int b = kt & 1, k0 = kt * 32;
        unsigned short* As = Sb + b * 8192;
        unsigned short* Bs = As + 4096;
#pragma unroll
        for (int i = 0; i < 2; i++) {
            int rb = wave * 32 + i * 16;
            gload_lds16(Ag + (size_t)(row0 + rb + lr) * KP + k0 + lp * 8, As + rb * 32);
            gload_lds16(Bg + (size_t)(col0 + rb + lr) * KP + k0 + lp * 8, Bs + rb * 32);
        }
    };

    stage(0);
#pragma unroll 1
    for (int kt = 0; kt < KP / 32; kt++) {
        __syncthreads();                 // buffer kt ready (drains vmcnt)
        if (kt < KP / 32 - 1) stage(kt + 1);   // prefetch overlaps MFMA below
        const unsigned short* As = Sb + (kt & 1) * 8192;
        const unsigned short* Bs = As + 4096;
        short8 af[4], bfr[4];
#pragma unroll
        for (int mt = 0; mt < 4; mt++)
            af[mt] = *(const short8*)(As + (wm * 64 + mt * 16 + l16) * 32 + quad * 8);
#pragma unroll
        for (int nt = 0; nt < 4; nt++)
            bfr[nt] = *(const short8*)(Bs + (wn * 64 + nt * 16 + l16) * 32 + quad * 8);
#pragma unroll
        for (int mt = 0; mt < 4; mt++)
#pragma unroll
            for (int nt = 0; nt < 4; nt++)
                acc[mt][nt] = __builtin_amdgcn_mfma_f32_16x16x32_bf16(
                    af[mt], bfr[nt], acc[mt][nt], 0, 0, 0);
    }

    // epilogue: two column-halves through LDS, grouped-run segment max
#pragma unroll 1
    for (int h = 0; h < 2; h++) {
        __syncthreads();
        if (wn == h) {
#pragma unroll
            for (int mt = 0; mt < 4; mt++)
#pragma unroll
                for (int nt = 0; nt < 4; nt++)
#pragma unroll
                    for (int reg = 0; reg < 4; reg++)
                        Dl[(wm * 64 + mt * 16 + quad * 4 + reg) * 66 + nt * 16 + l16] =
                            acc[mt][nt][reg];
        }
        __syncthreads();
        int r = tid >> 1, j0 = (tid & 1) * 32;
        float cur = Dl[r * 66 + j0];
        int cs = segs[h * 64 + j0];
#pragma unroll
        for (int j = 1; j < 32; j++) {
            int sgj = segs[h * 64 + j0 + j];
            float v = Dl[r * 66 + j0 + j];
            if (sgj == cs) {
                cur = fmaxf(cur, v);
            } else {
                atomicMax(&keys[(size_t)(row0 + r) * CC + cs], enc_f(cur));
                cs = sgj;
                cur = v;
            }
        }
        atomicMax(&keys[(size_t)(row0 + r) * CC + cs], enc_f(cur));
    }

    // completion counter: last of 32 blocks (16 col-blocks x 2 branches) for this
    // 128-row stripe computes softmax + loss for its rows
    __syncthreads();
    if (tid == 0) {
        __threadfence();
        last_sh = atomicAdd(&cnt[blockIdx.y], 1u);
    }
    __syncthreads();
    if (last_sh == 31u) {
        __threadfence();
        float part = 0.f;
#pragma unroll 1
        for (int it = 0; it < 32; it++) {
            size_t row = (size_t)blockIdx.y * 128 + it * 4 + wave;
            float t = dec_f(__hip_atomic_load(&keys_t[row * CC + lane],
                                              __ATOMIC_RELAXED, __HIP_MEMORY_SCOPE_AGENT));
            float s = dec_f(__hip_atomic_load(&keys_s[row * CC + lane],
                                              __ATOMIC_RELAXED, __HIP_MEMORY_SCOPE_AGENT));
            float m = t;
#pragma unroll
            for (int d = 32; d; d >>= 1) m = fmaxf(m, __shfl_xor(m, d));
            float e = expf(t - m);
            float sum = e;
#pragma unroll
            for (int d = 32; d; d >>= 1) sum += __shfl_xor(sum, d);
            float p = e / sum;
            float reli = 1.0f / sum - (1.0f / CC);  // max prob - 1/C
            float denta = p - s;
            float term = (1.0f + 0.5f * fabsf(reli)) * denta * denta;
#pragma unroll
            for (int d = 32; d; d >>= 1) term += __shfl_xor(term, d);
            part += term;
        }
        if (lane == 0) atomicAdd(out, part * (1.0f / BB));
    }
}

extern "C" void kernel_launch(void* const* d_in, const int* in_sizes, int n_in,
                              void* d_out, int out_size, void* d_ws, size_t ws_size,
                              hipStream_t stream) {
    const int*   sents = (const int*)d_in[0];
    const int*   seeds = (const int*)d_in[1];
    const int*   lens  = (const int*)d_in[2];
    const float* mask  = (const float*)d_in[4];
    const float* emb_t = (const float*)d_in[6];
    const float* emb_s = (const float*)d_in[7];
    float* out = (float*)d_out;

    char* w = (char*)d_ws;
    unsigned short* snt_t = (unsigned short*)w; w += (size_t)BB * KP * 2;
    unsigned short* snt_s = (unsigned short*)w; w += (size_t)BB * KP * 2;
    unsigned short* sd_t  = (unsigned short*)w; w += (size_t)SS * KP * 2;
    unsigned short* sd_s  = (unsigned short*)w; w += (size_t)SS * KP * 2;
    unsigned* keys_t = (unsigned*)w; w += (size_t)BB * CC * 4;
    unsigned* keys_s = (unsigned*)w; w += (size_t)BB * CC * 4;  // contiguous after keys_t
    int* seg = (int*)w;              w += (size_t)SS * 4;
    unsigned* cnt = (unsigned*)w;    w += 16 * 4;

    pool_kernel<<<BB + SS, 256, 0, stream>>>(sents, seeds, lens, mask, emb_t, emb_s,
                                             snt_t, snt_s, sd_t, sd_s,
                                             keys_t, seg, cnt, out);
    gemm_max_kernel<<<dim3(SS / 128, BB / 128, 2), 256, 0, stream>>>(
        snt_t, snt_s, sd_t, sd_s, seg, keys_t, keys_s, cnt, out);
}

// Round 5
// 196.574 us; speedup vs baseline: 1.1640x; 1.1640x over previous
//
#include <hip/hip_runtime.h>
#include <hip/hip_bf16.h>

#define BB 2048   // sentences
#define LL 64     // maxlen
#define SS 2048   // seeds
#define LSEED 8   // maxlen_seed
#define CC 64     // clusters
#define DD 300    // embedding dim
#define NC4 75    // DD / 4 float4 chunks
#define KP 320    // padded K for bf16 MFMA (10 x 32)

typedef __attribute__((ext_vector_type(8))) short short8;
typedef __attribute__((ext_vector_type(4))) float f32x4;

// ---- order-preserving float <-> uint for atomicMax ----
__device__ __forceinline__ unsigned enc_f(float f) {
    unsigned u = __float_as_uint(f);
    return (u & 0x80000000u) ? ~u : (u | 0x80000000u);
}
__device__ __forceinline__ float dec_f(unsigned k) {
    unsigned u = (k & 0x80000000u) ? (k ^ 0x80000000u) : ~k;
    return __uint_as_float(u);
}
// float -> bf16 bits, RNE
__device__ __forceinline__ unsigned short f2bf(float f) {
    unsigned u = __float_as_uint(f);
    u += 0x7fffu + ((u >> 16) & 1u);
    return (unsigned short)(u >> 16);
}
__device__ __forceinline__ void gload_lds16(const void* g, void* l) {
    __builtin_amdgcn_global_load_lds(
        (const __attribute__((address_space(1))) void*)g,
        (__attribute__((address_space(3))) void*)l, 16, 0, 0);
}

// ---- pooling (float4 gather, 3-group split) + fused init of keys/seg/out ----
// At the random-gather pattern wall (~3.2 TB/s) — measured invariant across codegens.
__global__ __launch_bounds__(256) void pool_kernel(
    const int* __restrict__ sents, const int* __restrict__ seeds,
    const int* __restrict__ lens, const float* __restrict__ mask,
    const float* __restrict__ emb_t, const float* __restrict__ emb_s,
    unsigned short* __restrict__ snt_t, unsigned short* __restrict__ snt_s,
    unsigned short* __restrict__ sd_t, unsigned short* __restrict__ sd_s,
    unsigned* __restrict__ keys_all, int* __restrict__ seg,
    float* __restrict__ out0) {
    const int bid = blockIdx.x, tid = threadIdx.x;

    // fused init: zero atomic-max keys (64 per block covers 2*BB*CC exactly)
    if (tid < 64) keys_all[bid * 64 + tid] = 0u;
    if (bid == 0) {
        if (tid == 0) *out0 = 0.f;
        // segment ids for all SS seeds: 8 per thread
        for (int i = tid * 8; i < tid * 8 + 8; i++) {
            int c = 0, cum = lens[0];
            while (i >= cum && c < CC - 1) { c++; cum += lens[c]; }
            seg[i] = c;
        }
    }

    __shared__ float4 pt[3 * NC4];
    __shared__ float4 ps[3 * NC4];
    __shared__ int toks[LL];
    __shared__ float msk[LL];
    __shared__ float denom_sh;

    const int g = tid / NC4;          // 0..2 (tid>=225 idle in gather)
    const int c = tid - g * NC4;      // float4 chunk within row

    if (bid < BB) {
        const int b = bid;
        if (tid < LL) {   // wave 0 exactly
            float v = mask[b * LL + tid];
            msk[tid] = v;
            toks[tid] = sents[b * LL + tid];
#pragma unroll
            for (int d = 32; d; d >>= 1) v += __shfl_xor(v, d);
            if (tid == 0) denom_sh = fmaxf(v, 1.0f);
        }
        __syncthreads();
        if (g < 3) {
            float4 at = {0.f, 0.f, 0.f, 0.f}, as = {0.f, 0.f, 0.f, 0.f};
#pragma unroll 4
            for (int l = g; l < LL; l += 3) {
                size_t o = (size_t)toks[l] * DD;
                float m = msk[l];
                float4 vt = *(const float4*)(emb_t + o + 4 * c);
                float4 vs = *(const float4*)(emb_s + o + 4 * c);
                at.x = fmaf(m, vt.x, at.x); at.y = fmaf(m, vt.y, at.y);
                at.z = fmaf(m, vt.z, at.z); at.w = fmaf(m, vt.w, at.w);
                as.x = fmaf(m, vs.x, as.x); as.y = fmaf(m, vs.y, as.y);
                as.z = fmaf(m, vs.z, as.z); as.w = fmaf(m, vs.w, as.w);
            }
            pt[g * NC4 + c] = at;
            ps[g * NC4 + c] = as;
        }
        __syncthreads();
        float scale = 1.0f / denom_sh;
        if (tid < 150) {
            int table = tid / NC4, cc = tid - table * NC4;
            const float4* P = table ? ps : pt;
            float4 a = P[cc], b2 = P[NC4 + cc], d2 = P[2 * NC4 + cc];
            ushort4 o;
            o.x = f2bf((a.x + b2.x + d2.x) * scale);
            o.y = f2bf((a.y + b2.y + d2.y) * scale);
            o.z = f2bf((a.z + b2.z + d2.z) * scale);
            o.w = f2bf((a.w + b2.w + d2.w) * scale);
            unsigned short* dst = (table ? snt_s : snt_t) + (size_t)b * KP + 4 * cc;
            *(ushort4*)dst = o;
        } else if (tid >= 160 && tid < 170) {  // zero tail dims [300,320)
            int k = tid - 160;                  // 0..9 -> 2 tables x 5 chunks
            unsigned short* dst = ((k < 5) ? snt_t : snt_s) + (size_t)b * KP + 300 + 4 * (k % 5);
            *(ushort4*)dst = (ushort4){0, 0, 0, 0};
        }
    } else {
        const int s = bid - BB;
        if (tid < LSEED) toks[tid] = seeds[s * LSEED + tid];
        __syncthreads();
        if (g < 3) {
            float4 at = {0.f, 0.f, 0.f, 0.f}, as = {0.f, 0.f, 0.f, 0.f};
#pragma unroll
            for (int l = g; l < LSEED; l += 3) {
                size_t o = (size_t)toks[l] * DD;
                float4 vt = *(const float4*)(emb_t + o + 4 * c);
                float4 vs = *(const float4*)(emb_s + o + 4 * c);
                at.x += vt.x; at.y += vt.y; at.z += vt.z; at.w += vt.w;
                as.x += vs.x; as.y += vs.y; as.z += vs.z; as.w += vs.w;
            }
            pt[g * NC4 + c] = at;
            ps[g * NC4 + c] = as;
        }
        __syncthreads();
        const float scale = 1.0f / LSEED;
        if (tid < 150) {
            int table = tid / NC4, cc = tid - table * NC4;
            const float4* P = table ? ps : pt;
            float4 a = P[cc], b2 = P[NC4 + cc], d2 = P[2 * NC4 + cc];
            ushort4 o;
            o.x = f2bf((a.x + b2.x + d2.x) * scale);
            o.y = f2bf((a.y + b2.y + d2.y) * scale);
            o.z = f2bf((a.z + b2.z + d2.z) * scale);
            o.w = f2bf((a.w + b2.w + d2.w) * scale);
            unsigned short* dst = (table ? sd_s : sd_t) + (size_t)s * KP + 4 * cc;
            *(ushort4*)dst = o;
        } else if (tid >= 160 && tid < 170) {
            int k = tid - 160;
            unsigned short* dst = ((k < 5) ? sd_t : sd_s) + (size_t)s * KP + 300 + 4 * (k % 5);
            *(ushort4*)dst = (ushort4){0, 0, 0, 0};
        }
    }
}

// ---- bf16 MFMA GEMM (pro = snt @ sd^T), 128x128, async LDS staging, fused segment-max ----
// Single-buffered staging: explicit double-buffering regressed (R4, 229 us) — the
// compiler inserts vmcnt(0) before ds_read (cannot prove LDS non-alias with the
// global_load_lds destination), serializing the "prefetch".
__global__ __launch_bounds__(256) void gemm_max_kernel(
    const unsigned short* __restrict__ snt_t, const unsigned short* __restrict__ snt_s,
    const unsigned short* __restrict__ sd_t, const unsigned short* __restrict__ sd_s,
    const int* __restrict__ seg,
    unsigned* __restrict__ keys_t, unsigned* __restrict__ keys_s) {
    const int branch = blockIdx.z;
    const unsigned short* Ag = branch ? snt_s : snt_t;
    const unsigned short* Bg = branch ? sd_s : sd_t;
    unsigned* keys = branch ? keys_s : keys_t;

    const int tid = threadIdx.x;
    const int wave = tid >> 6, lane = tid & 63;
    const int quad = lane >> 4, l16 = lane & 15;
    const int wm = wave >> 1, wn = wave & 1;   // 2x2 wave grid, 64x64 per wave
    const int row0 = blockIdx.y * 128, col0 = blockIdx.x * 128;

    // smem: staging A/B (2 x 128 x 32 bf16 = 16384 B) unioned with
    //       D half-tile (128 x 66 f32 = 33792 B), + segs[128]
    __shared__ __align__(16) char smem[33792 + 512];
    unsigned short* As = (unsigned short*)smem;           // [128][32]
    unsigned short* Bs = As + 128 * 32;
    float* Dl = (float*)smem;                              // [128][66]
    int* segs = (int*)(smem + 33792);

    if (tid < 128) segs[tid] = seg[col0 + tid];

    const int lr = lane >> 2, lp = lane & 3;   // staging: 4 lanes per row

    f32x4 acc[4][4];
#pragma unroll
    for (int i = 0; i < 4; i++)
#pragma unroll
        for (int j = 0; j < 4; j++) acc[i][j] = (f32x4)0.f;

#pragma unroll 1
    for (int kt = 0; kt < KP / 32; kt++) {
        const int k0 = kt * 32;
        __syncthreads();
        // async stage 128x32 of A and B: each wave 2 chunks of 16 rows per matrix
#pragma unroll
        for (int i = 0; i < 2; i++) {
            int rb = wave * 32 + i * 16;
            gload_lds16(Ag + (size_t)(row0 + rb + lr) * KP + k0 + lp * 8,
                        As + rb * 32);
            gload_lds16(Bg + (size_t)(col0 + rb + lr) * KP + k0 + lp * 8,
                        Bs + rb * 32);
        }
        __syncthreads();
        short8 af[4], bfr[4];
#pragma unroll
        for (int mt = 0; mt < 4; mt++)
            af[mt] = *(const short8*)(As + (wm * 64 + mt * 16 + l16) * 32 + quad * 8);
#pragma unroll
        for (int nt = 0; nt < 4; nt++)
            bfr[nt] = *(const short8*)(Bs + (wn * 64 + nt * 16 + l16) * 32 + quad * 8);
#pragma unroll
        for (int mt = 0; mt < 4; mt++)
#pragma unroll
            for (int nt = 0; nt < 4; nt++)
                acc[mt][nt] = __builtin_amdgcn_mfma_f32_16x16x32_bf16(
                    af[mt], bfr[nt], acc[mt][nt], 0, 0, 0);
    }

    // epilogue: two column-halves through LDS, grouped-run segment max
#pragma unroll 1
    for (int h = 0; h < 2; h++) {
        __syncthreads();
        if (wn == h) {
#pragma unroll
            for (int mt = 0; mt < 4; mt++)
#pragma unroll
                for (int nt = 0; nt < 4; nt++)
#pragma unroll
                    for (int reg = 0; reg < 4; reg++)
                        Dl[(wm * 64 + mt * 16 + quad * 4 + reg) * 66 + nt * 16 + l16] =
                            acc[mt][nt][reg];
        }
        __syncthreads();
        int r = tid >> 1, j0 = (tid & 1) * 32;
        float cur = Dl[r * 66 + j0];
        int cs = segs[h * 64 + j0];
#pragma unroll
        for (int j = 1; j < 32; j++) {
            int sgj = segs[h * 64 + j0 + j];
            float v = Dl[r * 66 + j0 + j];
            if (sgj == cs) {
                cur = fmaxf(cur, v);
            } else {
                atomicMax(&keys[(size_t)(row0 + r) * CC + cs], enc_f(cur));
                cs = sgj;
                cur = v;
            }
        }
        atomicMax(&keys[(size_t)(row0 + r) * CC + cs], enc_f(cur));
    }
}

// ---- per-row softmax + loss; one wave per row; one atomicAdd per block ----
__global__ __launch_bounds__(256) void loss_kernel(
    const unsigned* __restrict__ keys_t, const unsigned* __restrict__ keys_s,
    float* __restrict__ out) {
    int tid = threadIdx.x, w = tid >> 6, lane = tid & 63;
    int row = blockIdx.x * 4 + w;
    float t = dec_f(keys_t[row * CC + lane]);
    float s = dec_f(keys_s[row * CC + lane]);
    float m = t;
#pragma unroll
    for (int d = 32; d; d >>= 1) m = fmaxf(m, __shfl_xor(m, d));
    float e = expf(t - m);
    float sum = e;
#pragma unroll
    for (int d = 32; d; d >>= 1) sum += __shfl_xor(sum, d);
    float p = e / sum;
    float reli = 1.0f / sum - (1.0f / CC);  // max prob - 1/C
    float denta = p - s;
    float term = (1.0f + 0.5f * fabsf(reli)) * denta * denta;
#pragma unroll
    for (int d = 32; d; d >>= 1) term += __shfl_xor(term, d);
    __shared__ float blk[4];
    if (lane == 0) blk[w] = term;
    __syncthreads();
    if (tid == 0)
        atomicAdd(out, (blk[0] + blk[1] + blk[2] + blk[3]) * (1.0f / BB));
}

extern "C" void kernel_launch(void* const* d_in, const int* in_sizes, int n_in,
                              void* d_out, int out_size, void* d_ws, size_t ws_size,
                              hipStream_t stream) {
    const int*   sents = (const int*)d_in[0];
    const int*   seeds = (const int*)d_in[1];
    const int*   lens  = (const int*)d_in[2];
    const float* mask  = (const float*)d_in[4];
    const float* emb_t = (const float*)d_in[6];
    const float* emb_s = (const float*)d_in[7];
    float* out = (float*)d_out;

    char* w = (char*)d_ws;
    unsigned short* snt_t = (unsigned short*)w; w += (size_t)BB * KP * 2;
    unsigned short* snt_s = (unsigned short*)w; w += (size_t)BB * KP * 2;
    unsigned short* sd_t  = (unsigned short*)w; w += (size_t)SS * KP * 2;
    unsigned short* sd_s  = (unsigned short*)w; w += (size_t)SS * KP * 2;
    unsigned* keys_t = (unsigned*)w; w += (size_t)BB * CC * 4;
    unsigned* keys_s = (unsigned*)w; w += (size_t)BB * CC * 4;  // contiguous after keys_t
    int* seg = (int*)w;              w += (size_t)SS * 4;

    pool_kernel<<<BB + SS, 256, 0, stream>>>(sents, seeds, lens, mask, emb_t, emb_s,
                                             snt_t, snt_s, sd_t, sd_s,
                                             keys_t, seg, out);
    gemm_max_kernel<<<dim3(SS / 128, BB / 128, 2), 256, 0, stream>>>(
        snt_t, snt_s, sd_t, sd_s, seg, keys_t, keys_s);
    loss_kernel<<<BB / 4, 256, 0, stream>>>(keys_t, keys_s, out);
}